// Round 3
// baseline (684.170 us; speedup 1.0000x reference)
//
#include <hip/hip_runtime.h>
#include <math.h>

// DNA-GNN: N=100000, E=3200000, C=8, HEADS=2, d_head=4, 3 layers.
// glin GROUPS=8, cin=cout=1 => per-channel scale+bias.
//
// Round 3: atomic-free-ish CSR via bucketed counting sort.
//   bucket k = dst >> 6 (64 nodes/bucket, B=1563 buckets)
//   phaseA: per-block LDS bucket histogram -> histG[k][blk]
//   scan  : parallel 3-kernel exclusive scan of flat histG (bucket-major)
//   phaseC: rank via LDS atomics, scatter packed (src | dl<<17) into ebuf
//   dinv  : per-bucket LDS dst count (+1 self) -> rsqrt
//   agg   : 1 WG per bucket; q + fp32 accumulators in LDS (ds_add_f32);
//           self-loop handled in finalize (never stored in ebuf)
//
// ws: xall n*32 f32 | dinv n f32 | ebuf E i32 | histG B*NBLK i32 | bsum i32

#define NPB   64      // nodes per bucket
#define MAXB  1600    // >= ceil(100000/64)=1563
#define CH    16384   // edges per phaseA/phaseC block

__global__ void phaseA_hist(const int* __restrict__ eidx, int* __restrict__ histG,
                            int E, int NBLK, int B) {
    __shared__ int hist[MAXB];
    int t = threadIdx.x, b = blockIdx.x;
    for (int i = t; i < B; i += 256) hist[i] = 0;
    __syncthreads();
    int base = b * CH;
#pragma unroll
    for (int it = 0; it < CH / 256; it++) {
        int e = base + it * 256 + t;
        if (e < E) atomicAdd(&hist[eidx[E + e] >> 6], 1);
    }
    __syncthreads();
    for (int i = t; i < B; i += 256) histG[(size_t)i * NBLK + b] = hist[i];
}

// per-1024-chunk sums
__global__ void scan_l1(const int* __restrict__ data, int* __restrict__ bsum, int M) {
    __shared__ int sd[256];
    int t = threadIdx.x, b = blockIdx.x;
    int base = b * 1024 + t * 4;
    int ts = 0;
#pragma unroll
    for (int k = 0; k < 4; k++) { int i = base + k; if (i < M) ts += data[i]; }
    sd[t] = ts; __syncthreads();
    for (int s = 128; s > 0; s >>= 1) { if (t < s) sd[t] += sd[t + s]; __syncthreads(); }
    if (t == 0) bsum[b] = sd[0];
}

// single-WG exclusive scan of chunk sums (NB2 <= 512)
__global__ void scan_l2(int* __restrict__ bsum, int NB2) {
    __shared__ int sd[512];
    int t = threadIdx.x;
    int v = (t < NB2) ? bsum[t] : 0;
    sd[t] = v; __syncthreads();
    for (int o = 1; o < 512; o <<= 1) {
        int u = 0; if (t >= o) u = sd[t - o];
        __syncthreads(); sd[t] += u; __syncthreads();
    }
    if (t < NB2) bsum[t] = sd[t] - v;   // exclusive
}

// per-chunk exclusive scan, in place
__global__ void scan_l3(int* __restrict__ data, const int* __restrict__ bsum, int M) {
    __shared__ int sd[256];
    int t = threadIdx.x, b = blockIdx.x;
    int base = b * 1024 + t * 4;
    int c[4]; int ts = 0;
#pragma unroll
    for (int k = 0; k < 4; k++) { int i = base + k; c[k] = (i < M) ? data[i] : 0; ts += c[k]; }
    sd[t] = ts; __syncthreads();
    for (int o = 1; o < 256; o <<= 1) {
        int u = 0; if (t >= o) u = sd[t - o];
        __syncthreads(); sd[t] += u; __syncthreads();
    }
    int off = bsum[b] + sd[t] - ts;
#pragma unroll
    for (int k = 0; k < 4; k++) {
        int i = base + k;
        if (i < M) { data[i] = off; off += c[k]; }
    }
}

__global__ void phaseC_scatter(const int* __restrict__ eidx, const int* __restrict__ histG,
                               int* __restrict__ ebuf, int E, int NBLK, int B) {
    __shared__ int lofs[MAXB];
    int t = threadIdx.x, b = blockIdx.x;
    for (int i = t; i < B; i += 256) lofs[i] = histG[(size_t)i * NBLK + b];
    __syncthreads();
    int base = b * CH;
#pragma unroll
    for (int it = 0; it < CH / 256; it++) {
        int e = base + it * 256 + t;
        if (e < E) {
            int s = eidx[e], d = eidx[E + e];
            int k = d >> 6, dl = d & 63;
            int pos = atomicAdd(&lofs[k], 1);
            ebuf[pos] = s | (dl << 17);
        }
    }
}

__global__ void dinv_kernel(const int* __restrict__ ebuf, const int* __restrict__ histG,
                            float* __restrict__ dinv, int E, int NBLK, int B, int n) {
    __shared__ int cnt[NPB];
    int t = threadIdx.x, k = blockIdx.x;
    if (t < NPB) cnt[t] = 0;
    __syncthreads();
    int start = histG[(size_t)k * NBLK];
    int end = (k + 1 < B) ? histG[(size_t)(k + 1) * NBLK] : E;
    for (int slot = start + t; slot < end; slot += 256)
        atomicAdd(&cnt[ebuf[slot] >> 17], 1);
    __syncthreads();
    if (t < NPB) {
        int d = k * NPB + t;
        if (d < n) dinv[d] = rsqrtf((float)(cnt[t] + 1));
    }
}

// h0 = relu([emb_table[node_index], x] @ W1 + b1) -> xall layer 0
__global__ void node_init(const float* __restrict__ x, const int* __restrict__ nidx,
                          const float* __restrict__ emb, const float* __restrict__ W1,
                          const float* __restrict__ b1, float* __restrict__ xall, int n) {
    int i = blockIdx.x * blockDim.x + threadIdx.x;
    if (i >= n) return;
    float in[24];
    int ni = nidx[i];
    const float4* ep = (const float4*)(emb + (size_t)ni * 8);
    float4 e0 = ep[0], e1 = ep[1];
    in[0] = e0.x; in[1] = e0.y; in[2] = e0.z; in[3] = e0.w;
    in[4] = e1.x; in[5] = e1.y; in[6] = e1.z; in[7] = e1.w;
    const float4* xp = (const float4*)(x + (size_t)i * 16);
#pragma unroll
    for (int t = 0; t < 4; t++) {
        float4 v = xp[t];
        in[8 + 4 * t + 0] = v.x; in[8 + 4 * t + 1] = v.y;
        in[8 + 4 * t + 2] = v.z; in[8 + 4 * t + 3] = v.w;
    }
    float acc[8];
#pragma unroll
    for (int j = 0; j < 8; j++) acc[j] = b1[j];
#pragma unroll
    for (int t = 0; t < 24; t++) {
        float xv = in[t];
#pragma unroll
        for (int j = 0; j < 8; j++) acc[j] = fmaf(xv, W1[t * 8 + j], acc[j]);
    }
    float* o = xall + (size_t)i * 32;
#pragma unroll
    for (int j = 0; j < 8; j++) o[j] = fmaxf(acc[j], 0.0f);
}

// attention output for one edge given gathered src rows xs[8*Li] and scaled q
template <int Li>
__device__ __forceinline__ void attn_out(const float* xs, const float* qv,
                                         const float* __restrict__ wk, const float* __restrict__ bk,
                                         const float* __restrict__ wv, const float* __restrict__ bv,
                                         float* out) {
    float score[2][Li];
#pragma unroll
    for (int l = 0; l < Li; l++) {
#pragma unroll
        for (int h = 0; h < 2; h++) {
            float sc = 0.f;
#pragma unroll
            for (int dd = 0; dd < 4; dd++) {
                int c = h * 4 + dd;
                sc = fmaf(qv[c], fmaf(xs[l * 8 + c], wk[c], bk[c]), sc);
            }
            score[h][l] = 0.5f * sc;
        }
    }
    float attn[2][Li];
#pragma unroll
    for (int h = 0; h < 2; h++) {
        float m = score[h][0];
#pragma unroll
        for (int l = 1; l < Li; l++) m = fmaxf(m, score[h][l]);
        float ssum = 0.f;
#pragma unroll
        for (int l = 0; l < Li; l++) { attn[h][l] = __expf(score[h][l] - m); ssum += attn[h][l]; }
        float inv = 1.0f / ssum;
#pragma unroll
        for (int l = 0; l < Li; l++) attn[h][l] *= inv;
    }
#pragma unroll
    for (int c = 0; c < 8; c++) {
        int h = c >> 2;
        float o = 0.f;
#pragma unroll
        for (int l = 0; l < Li; l++) o = fmaf(attn[h][l], fmaf(xs[l * 8 + c], wv[c], bv[c]), o);
        out[c] = o;
    }
}

template <int Li>
__global__ void agg_bucket(const int* __restrict__ ebuf, const int* __restrict__ histG,
                           float* __restrict__ xall, const float* __restrict__ dinv,
                           const float* __restrict__ wq, const float* __restrict__ bq,
                           const float* __restrict__ wk, const float* __restrict__ bk,
                           const float* __restrict__ wv, const float* __restrict__ bv,
                           int E, int NBLK, int B, int n) {
    __shared__ float qb[8][NPB + 1];
    __shared__ float accb[8][NPB + 1];
    int t = threadIdx.x, k = blockIdx.x;
    for (int i = t; i < 8 * (NPB + 1); i += 256) ((float*)accb)[i] = 0.f;
    if (t < NPB) {
        int d = k * NPB + t;
        if (d < n) {
            const float4* qp = (const float4*)(xall + (size_t)d * 32 + (Li - 1) * 8);
            float4 q0 = qp[0], q1 = qp[1];
            float qv[8] = { q0.x, q0.y, q0.z, q0.w, q1.x, q1.y, q1.z, q1.w };
#pragma unroll
            for (int c = 0; c < 8; c++) qb[c][t] = fmaf(qv[c], wq[c], bq[c]);
        }
    }
    __syncthreads();
    int start = histG[(size_t)k * NBLK];
    int end = (k + 1 < B) ? histG[(size_t)(k + 1) * NBLK] : E;
    for (int slot = start + t; slot < end; slot += 256) {
        int w = ebuf[slot];
        int s = w & 131071, dl = w >> 17;
        float xs[8 * Li];
        const float4* sp = (const float4*)(xall + (size_t)s * 32);
#pragma unroll
        for (int u = 0; u < 2 * Li; u++) {
            float4 v = sp[u];
            xs[4 * u + 0] = v.x; xs[4 * u + 1] = v.y;
            xs[4 * u + 2] = v.z; xs[4 * u + 3] = v.w;
        }
        float qv[8];
#pragma unroll
        for (int c = 0; c < 8; c++) qv[c] = qb[c][dl];
        float o[8];
        attn_out<Li>(xs, qv, wk, bk, wv, bv, o);
        float ns = dinv[s];
#pragma unroll
        for (int c = 0; c < 8; c++) atomicAdd(&accb[c][dl], o[c] * ns);
    }
    __syncthreads();
    if (t < NPB) {
        int d = k * NPB + t;
        if (d < n) {
            float qv[8];
#pragma unroll
            for (int c = 0; c < 8; c++) qv[c] = qb[c][t];
            float xs[8 * Li];
            const float4* sp = (const float4*)(xall + (size_t)d * 32);
#pragma unroll
            for (int u = 0; u < 2 * Li; u++) {
                float4 v = sp[u];
                xs[4 * u + 0] = v.x; xs[4 * u + 1] = v.y;
                xs[4 * u + 2] = v.z; xs[4 * u + 3] = v.w;
            }
            float so[8];
            attn_out<Li>(xs, qv, wk, bk, wv, bv, so);
            float nd = dinv[d];
            float* orow = xall + (size_t)d * 32 + Li * 8;
#pragma unroll
            for (int c = 0; c < 8; c++) {
                float total = accb[c][t] + nd * so[c];
                orow[c] = fmaxf(nd * total, 0.f);
            }
        }
    }
}

__global__ void classify(const float* __restrict__ xall, const float* __restrict__ W2,
                         const float* __restrict__ b2, float* __restrict__ out, int n) {
    int i = blockIdx.x * blockDim.x + threadIdx.x;
    if (i >= n) return;
    const float* h = xall + (size_t)i * 32 + 24;
    float z0 = b2[0], z1 = b2[1];
#pragma unroll
    for (int c = 0; c < 8; c++) {
        z0 = fmaf(h[c], W2[c * 2 + 0], z0);
        z1 = fmaf(h[c], W2[c * 2 + 1], z1);
    }
    float m = fmaxf(z0, z1);
    float lse = m + logf(__expf(z0 - m) + __expf(z1 - m));
    ((float2*)out)[i] = make_float2(z0 - lse, z1 - lse);
}

extern "C" void kernel_launch(void* const* d_in, const int* in_sizes, int n_in,
                              void* d_out, int out_size, void* d_ws, size_t ws_size,
                              hipStream_t stream) {
    const float* x    = (const float*)d_in[0];
    const int*   nidx = (const int*)d_in[1];
    const int*   eidx = (const int*)d_in[3];
    const float* emb  = (const float*)d_in[5];
    const float* W1   = (const float*)d_in[6];
    const float* b1   = (const float*)d_in[7];
    const float* Wq   = (const float*)d_in[8];
    const float* bq   = (const float*)d_in[9];
    const float* Wk   = (const float*)d_in[10];
    const float* bk   = (const float*)d_in[11];
    const float* Wv   = (const float*)d_in[12];
    const float* bv   = (const float*)d_in[13];
    const float* W2   = (const float*)d_in[14];
    const float* b2   = (const float*)d_in[15];
    float* out = (float*)d_out;

    const int n = in_sizes[0] / 16;            // 100000
    const int E = in_sizes[3] / 2;             // 3200000
    const int B = (n + NPB - 1) / NPB;         // 1563 buckets
    const int NBLK = (E + CH - 1) / CH;        // 196 chunks
    const int M = B * NBLK;                    // flat histogram size
    const int NB2 = (M + 1023) / 1024;         // 300 scan chunks

    char* wsp = (char*)d_ws;
    float* xall  = (float*)wsp;  wsp += (size_t)n * 32 * 4;
    float* dinv  = (float*)wsp;  wsp += (size_t)n * 4;
    int*   ebuf  = (int*)wsp;    wsp += (size_t)E * 4;
    int*   histG = (int*)wsp;    wsp += (size_t)M * 4;
    int*   bsum  = (int*)wsp;

    dim3 blk(256);
    dim3 gn((n + 255) / 256);

    phaseA_hist<<<NBLK, blk, 0, stream>>>(eidx, histG, E, NBLK, B);
    scan_l1<<<NB2, blk, 0, stream>>>(histG, bsum, M);
    scan_l2<<<1, 512, 0, stream>>>(bsum, NB2);
    scan_l3<<<NB2, blk, 0, stream>>>(histG, bsum, M);
    phaseC_scatter<<<NBLK, blk, 0, stream>>>(eidx, histG, ebuf, E, NBLK, B);
    dinv_kernel<<<B, blk, 0, stream>>>(ebuf, histG, dinv, E, NBLK, B, n);
    node_init<<<gn, blk, 0, stream>>>(x, nidx, emb, W1, b1, xall, n);

    agg_bucket<1><<<B, blk, 0, stream>>>(ebuf, histG, xall, dinv, Wq, bq, Wk, bk, Wv, bv, E, NBLK, B, n);
    agg_bucket<2><<<B, blk, 0, stream>>>(ebuf, histG, xall, dinv, Wq + 8, bq + 8, Wk + 8, bk + 8, Wv + 8, bv + 8, E, NBLK, B, n);
    agg_bucket<3><<<B, blk, 0, stream>>>(ebuf, histG, xall, dinv, Wq + 16, bq + 16, Wk + 16, bk + 16, Wv + 16, bv + 16, E, NBLK, B, n);

    classify<<<gn, blk, 0, stream>>>(xall, W2, b2, out, n);
}

// Round 4
// 454.848 us; speedup vs baseline: 1.5042x; 1.5042x over previous
//
#include <hip/hip_runtime.h>
#include <math.h>

// DNA-GNN: N=100000, E=3200000, C=8, HEADS=2, d_head=4, 3 layers.
// glin GROUPS=8, cin=cout=1 => per-channel scale+bias.
//
// Round 4: bucket counting-sort -> full dst-sorted CSR (in-place via LDS
// staging), then atomic-free 8-lanes-per-dst register aggregation
// (round-2 scheme). Self-loop = virtual slot 0 in the agg loop (not stored).
// Layout: x0 (N,16) 64B rows [ch0-7, dinv, pad]; x12 (N,16) [layer1 | layer2].
// classify fused into agg layer 3.
//
// ws: x0 n*16 f | x12 n*16 f | ebuf E i32 | off (n+1) i32 | histG M i32 | bsum

#define NPB   64
#define MAXB  1600
#define CH    16384
#define SEGCAP 12288   // max edges per bucket staged in LDS (mean 2048, max ~2.4k)

__global__ void phaseA_hist(const int* __restrict__ eidx, int* __restrict__ histG,
                            int E, int NBLK, int B) {
    __shared__ int hist[MAXB];
    int t = threadIdx.x, b = blockIdx.x;
    for (int i = t; i < B; i += 256) hist[i] = 0;
    __syncthreads();
    int base = b * CH;
#pragma unroll
    for (int it = 0; it < CH / 256; it++) {
        int e = base + it * 256 + t;
        if (e < E) atomicAdd(&hist[eidx[E + e] >> 6], 1);
    }
    __syncthreads();
    for (int i = t; i < B; i += 256) histG[(size_t)i * NBLK + b] = hist[i];
}

__global__ void scan_l1(const int* __restrict__ data, int* __restrict__ bsum, int M) {
    __shared__ int sd[256];
    int t = threadIdx.x, b = blockIdx.x;
    int base = b * 1024 + t * 4;
    int ts = 0;
#pragma unroll
    for (int k = 0; k < 4; k++) { int i = base + k; if (i < M) ts += data[i]; }
    sd[t] = ts; __syncthreads();
    for (int s = 128; s > 0; s >>= 1) { if (t < s) sd[t] += sd[t + s]; __syncthreads(); }
    if (t == 0) bsum[b] = sd[0];
}

__global__ void scan_l2(int* __restrict__ bsum, int NB2) {
    __shared__ int sd[512];
    int t = threadIdx.x;
    int v = (t < NB2) ? bsum[t] : 0;
    sd[t] = v; __syncthreads();
    for (int o = 1; o < 512; o <<= 1) {
        int u = 0; if (t >= o) u = sd[t - o];
        __syncthreads(); sd[t] += u; __syncthreads();
    }
    if (t < NB2) bsum[t] = sd[t] - v;
}

__global__ void scan_l3(int* __restrict__ data, const int* __restrict__ bsum, int M) {
    __shared__ int sd[256];
    int t = threadIdx.x, b = blockIdx.x;
    int base = b * 1024 + t * 4;
    int c[4]; int ts = 0;
#pragma unroll
    for (int k = 0; k < 4; k++) { int i = base + k; c[k] = (i < M) ? data[i] : 0; ts += c[k]; }
    sd[t] = ts; __syncthreads();
    for (int o = 1; o < 256; o <<= 1) {
        int u = 0; if (t >= o) u = sd[t - o];
        __syncthreads(); sd[t] += u; __syncthreads();
    }
    int off = bsum[b] + sd[t] - ts;
#pragma unroll
    for (int k = 0; k < 4; k++) {
        int i = base + k;
        if (i < M) { data[i] = off; off += c[k]; }
    }
}

__global__ void phaseC_scatter(const int* __restrict__ eidx, const int* __restrict__ histG,
                               int* __restrict__ ebuf, int E, int NBLK, int B) {
    __shared__ int lofs[MAXB];
    int t = threadIdx.x, b = blockIdx.x;
    for (int i = t; i < B; i += 256) lofs[i] = histG[(size_t)i * NBLK + b];
    __syncthreads();
    int base = b * CH;
#pragma unroll
    for (int it = 0; it < CH / 256; it++) {
        int e = base + it * 256 + t;
        if (e < E) {
            int s = eidx[e], d = eidx[E + e];
            int pos = atomicAdd(&lofs[d >> 6], 1);
            ebuf[pos] = s | ((d & 63) << 17);
        }
    }
}

// One WG per bucket: stage segment in LDS, per-dl count + scan -> off/dinv,
// scatter src (dl-sorted) back into ebuf in place.
__global__ void bucket_csr(int* __restrict__ ebuf, const int* __restrict__ histG,
                           int* __restrict__ off, float* __restrict__ x0,
                           int E, int NBLK, int B, int n) {
    __shared__ int seg[SEGCAP];
    __shared__ int cnt[NPB];
    __shared__ int fillp[NPB];
    int t = threadIdx.x, k = blockIdx.x;
    if (t < NPB) cnt[t] = 0;
    int start = histG[(size_t)k * NBLK];
    int end = (k + 1 < B) ? histG[(size_t)(k + 1) * NBLK] : E;
    int len = end - start;
    if (len > SEGCAP) len = SEGCAP;   // unreachable for this input distribution
    __syncthreads();
    for (int i = t; i < len; i += 256) {
        int w = ebuf[start + i];
        seg[i] = w;
        atomicAdd(&cnt[w >> 17], 1);
    }
    __syncthreads();
    if (t < NPB) {
        int v = cnt[t];
        int x = v;
#pragma unroll
        for (int o2 = 1; o2 < 64; o2 <<= 1) {
            int y = __shfl_up(x, o2);
            if (t >= o2) x += y;
        }
        int excl = x - v;
        fillp[t] = excl;
        int d = k * NPB + t;
        if (d < n) {
            off[d] = start + excl;
            x0[(size_t)d * 16 + 8] = rsqrtf((float)(v + 1));  // +1 self-loop
        }
    }
    if (k == 0 && t == 0) off[n] = E;
    __syncthreads();
    for (int i = t; i < len; i += 256) {
        int w = seg[i];
        int pos = atomicAdd(&fillp[w >> 17], 1);
        ebuf[start + pos] = w & 131071;
    }
}

// h0 = relu([emb_table[node_index], x] @ W1 + b1) -> x0 channels 0..7
__global__ void node_init(const float* __restrict__ x, const int* __restrict__ nidx,
                          const float* __restrict__ emb, const float* __restrict__ W1,
                          const float* __restrict__ b1, float* __restrict__ x0, int n) {
    int i = blockIdx.x * blockDim.x + threadIdx.x;
    if (i >= n) return;
    float in[24];
    int ni = nidx[i];
    const float4* ep = (const float4*)(emb + (size_t)ni * 8);
    float4 e0 = ep[0], e1 = ep[1];
    in[0] = e0.x; in[1] = e0.y; in[2] = e0.z; in[3] = e0.w;
    in[4] = e1.x; in[5] = e1.y; in[6] = e1.z; in[7] = e1.w;
    const float4* xp = (const float4*)(x + (size_t)i * 16);
#pragma unroll
    for (int t = 0; t < 4; t++) {
        float4 v = xp[t];
        in[8 + 4 * t + 0] = v.x; in[8 + 4 * t + 1] = v.y;
        in[8 + 4 * t + 2] = v.z; in[8 + 4 * t + 3] = v.w;
    }
    float acc[8];
#pragma unroll
    for (int j = 0; j < 8; j++) acc[j] = b1[j];
#pragma unroll
    for (int t = 0; t < 24; t++) {
        float xv = in[t];
#pragma unroll
        for (int j = 0; j < 8; j++) acc[j] = fmaf(xv, W1[t * 8 + j], acc[j]);
    }
    float* o = x0 + (size_t)i * 16;
#pragma unroll
    for (int j = 0; j < 8; j++) o[j] = fmaxf(acc[j], 0.0f);
}

template <int Li>
__device__ __forceinline__ void attn_out(const float* xs, const float* qv,
                                         const float* __restrict__ wk, const float* __restrict__ bk,
                                         const float* __restrict__ wv, const float* __restrict__ bv,
                                         float* out) {
    float score[2][Li];
#pragma unroll
    for (int l = 0; l < Li; l++) {
#pragma unroll
        for (int h = 0; h < 2; h++) {
            float sc = 0.f;
#pragma unroll
            for (int dd = 0; dd < 4; dd++) {
                int c = h * 4 + dd;
                sc = fmaf(qv[c], fmaf(xs[l * 8 + c], wk[c], bk[c]), sc);
            }
            score[h][l] = 0.5f * sc;
        }
    }
    float attn[2][Li];
#pragma unroll
    for (int h = 0; h < 2; h++) {
        float m = score[h][0];
#pragma unroll
        for (int l = 1; l < Li; l++) m = fmaxf(m, score[h][l]);
        float ssum = 0.f;
#pragma unroll
        for (int l = 0; l < Li; l++) { attn[h][l] = __expf(score[h][l] - m); ssum += attn[h][l]; }
        float inv = 1.0f / ssum;
#pragma unroll
        for (int l = 0; l < Li; l++) attn[h][l] *= inv;
    }
#pragma unroll
    for (int c = 0; c < 8; c++) {
        int h = c >> 2;
        float o = 0.f;
#pragma unroll
        for (int l = 0; l < Li; l++) o = fmaf(attn[h][l], fmaf(xs[l * 8 + c], wv[c], bv[c]), o);
        out[c] = o;
    }
}

// 8 lanes per dst; virtual slot 0 = self-loop; register acc + shfl_xor reduce.
// LAST: fuse classifier + log_softmax, write float2 logits instead of x12.
template <int Li, bool LAST>
__global__ void agg_layer(const int* __restrict__ ssrc, const int* __restrict__ off,
                          const float* __restrict__ x0, const float* __restrict__ x12,
                          const float* __restrict__ qsrc,   // + per-d offset qoff
                          int qoff, float* __restrict__ xout, int ooff,
                          const float* __restrict__ wq, const float* __restrict__ bq,
                          const float* __restrict__ wk, const float* __restrict__ bk,
                          const float* __restrict__ wv, const float* __restrict__ bv,
                          const float* __restrict__ W2, const float* __restrict__ b2,
                          float* __restrict__ out, int n) {
    int tid = blockIdx.x * blockDim.x + threadIdx.x;
    int d = tid >> 3, t = tid & 7;
    if (d >= n) return;
    int lo = off[d], cnt = off[d + 1] - lo;

    const float4* qp = (const float4*)(qsrc + (size_t)d * 16 + qoff);
    float4 q0 = qp[0], q1 = qp[1];
    float qv[8] = { q0.x, q0.y, q0.z, q0.w, q1.x, q1.y, q1.z, q1.w };
#pragma unroll
    for (int c = 0; c < 8; c++) qv[c] = fmaf(qv[c], wq[c], bq[c]);

    float acc[8];
#pragma unroll
    for (int c = 0; c < 8; c++) acc[c] = 0.f;

    for (int j = t; j < cnt + 1; j += 8) {
        int s = (j == 0) ? d : ssrc[lo + j - 1];
        float xs[8 * Li];
        const float4* p0 = (const float4*)(x0 + (size_t)s * 16);
        float4 a = p0[0], b = p0[1];
        xs[0] = a.x; xs[1] = a.y; xs[2] = a.z; xs[3] = a.w;
        xs[4] = b.x; xs[5] = b.y; xs[6] = b.z; xs[7] = b.w;
        float ns = x0[(size_t)s * 16 + 8];
        if (Li >= 2) {
            const float4* p1 = (const float4*)(x12 + (size_t)s * 16);
            float4 u = p1[0], v = p1[1];
            xs[8] = u.x; xs[9] = u.y; xs[10] = u.z; xs[11] = u.w;
            xs[12] = v.x; xs[13] = v.y; xs[14] = v.z; xs[15] = v.w;
        }
        if (Li >= 3) {
            const float4* p2 = (const float4*)(x12 + (size_t)s * 16 + 8);
            float4 u = p2[0], v = p2[1];
            xs[16] = u.x; xs[17] = u.y; xs[18] = u.z; xs[19] = u.w;
            xs[20] = v.x; xs[21] = v.y; xs[22] = v.z; xs[23] = v.w;
        }
        float o[8];
        attn_out<Li>(xs, qv, wk, bk, wv, bv, o);
#pragma unroll
        for (int c = 0; c < 8; c++) acc[c] = fmaf(o[c], ns, acc[c]);
    }
#pragma unroll
    for (int m = 1; m < 8; m <<= 1) {
#pragma unroll
        for (int c = 0; c < 8; c++) acc[c] += __shfl_xor(acc[c], m);
    }
    float nd = x0[(size_t)d * 16 + 8];
    if (!LAST) {
        xout[(size_t)d * 16 + ooff + t] = fmaxf(acc[t] * nd, 0.f);
    } else if (t == 0) {
        float z0 = b2[0], z1 = b2[1];
#pragma unroll
        for (int c = 0; c < 8; c++) {
            float h = fmaxf(acc[c] * nd, 0.f);
            z0 = fmaf(h, W2[c * 2 + 0], z0);
            z1 = fmaf(h, W2[c * 2 + 1], z1);
        }
        float m = fmaxf(z0, z1);
        float lse = m + logf(__expf(z0 - m) + __expf(z1 - m));
        ((float2*)out)[d] = make_float2(z0 - lse, z1 - lse);
    }
}

extern "C" void kernel_launch(void* const* d_in, const int* in_sizes, int n_in,
                              void* d_out, int out_size, void* d_ws, size_t ws_size,
                              hipStream_t stream) {
    const float* x    = (const float*)d_in[0];
    const int*   nidx = (const int*)d_in[1];
    const int*   eidx = (const int*)d_in[3];
    const float* emb  = (const float*)d_in[5];
    const float* W1   = (const float*)d_in[6];
    const float* b1   = (const float*)d_in[7];
    const float* Wq   = (const float*)d_in[8];
    const float* bq   = (const float*)d_in[9];
    const float* Wk   = (const float*)d_in[10];
    const float* bk   = (const float*)d_in[11];
    const float* Wv   = (const float*)d_in[12];
    const float* bv   = (const float*)d_in[13];
    const float* W2   = (const float*)d_in[14];
    const float* b2   = (const float*)d_in[15];
    float* out = (float*)d_out;

    const int n = in_sizes[0] / 16;            // 100000
    const int E = in_sizes[3] / 2;             // 3200000
    const int B = (n + NPB - 1) / NPB;         // 1563
    const int NBLK = (E + CH - 1) / CH;        // 196
    const int M = B * NBLK;
    const int NB2 = (M + 1023) / 1024;

    char* wsp = (char*)d_ws;
    float* x0    = (float*)wsp;  wsp += (size_t)n * 16 * 4;
    float* x12   = (float*)wsp;  wsp += (size_t)n * 16 * 4;
    int*   ebuf  = (int*)wsp;    wsp += (size_t)E * 4;
    int*   off   = (int*)wsp;    wsp += (size_t)(n + 1) * 4;
    int*   histG = (int*)wsp;    wsp += (size_t)M * 4;
    int*   bsum  = (int*)wsp;

    dim3 blk(256);
    dim3 gn((n + 255) / 256);
    dim3 ga(((size_t)n * 8 + 255) / 256);

    phaseA_hist<<<NBLK, blk, 0, stream>>>(eidx, histG, E, NBLK, B);
    scan_l1<<<NB2, blk, 0, stream>>>(histG, bsum, M);
    scan_l2<<<1, 512, 0, stream>>>(bsum, NB2);
    scan_l3<<<NB2, blk, 0, stream>>>(histG, bsum, M);
    phaseC_scatter<<<NBLK, blk, 0, stream>>>(eidx, histG, ebuf, E, NBLK, B);
    bucket_csr<<<B, blk, 0, stream>>>(ebuf, histG, off, x0, E, NBLK, B, n);
    node_init<<<gn, blk, 0, stream>>>(x, nidx, emb, W1, b1, x0, n);

    agg_layer<1, false><<<ga, blk, 0, stream>>>(ebuf, off, x0, x12, x0, 0, x12, 0,
        Wq, bq, Wk, bk, Wv, bv, W2, b2, out, n);
    agg_layer<2, false><<<ga, blk, 0, stream>>>(ebuf, off, x0, x12, x12, 0, x12, 8,
        Wq + 8, bq + 8, Wk + 8, bk + 8, Wv + 8, bv + 8, W2, b2, out, n);
    agg_layer<3, true><<<ga, blk, 0, stream>>>(ebuf, off, x0, x12, x12, 8, nullptr, 0,
        Wq + 16, bq + 16, Wk + 16, bk + 16, Wv + 16, bv + 16, W2, b2, out, n);
}

// Round 5
// 302.916 us; speedup vs baseline: 2.2586x; 1.5016x over previous
//
#include <hip/hip_runtime.h>
#include <math.h>

// DNA-GNN: N=100000, E=3200000, C=8, HEADS=2, d_head=4, 3 layers.
// glin GROUPS=8, cin=cout=1 => per-channel scale+bias.
//
// Round 5: fp16 gather tables to beat the per-XCD 4-MiB L2.
//   A: (N,32B) [8 x fp16 h0][f32 dinv][pad]        -> 3.2 MB (layer-1 gathers)
//   U: (N,64B) [24 x fp16 h0|h1|h2][f32 dinv][pad] -> 6.4 MB, 1 line/edge (L2/L3)
// All math fp32; only gathered features are fp16.
// CSR build: bucket counting sort (round-4 scheme), self-loop virtual.

#define NPB   64
#define MAXB  1600
#define CH    16384
#define SEGCAP 12288

typedef _Float16 half8 __attribute__((ext_vector_type(8)));

__global__ void phaseA_hist(const int* __restrict__ eidx, int* __restrict__ histG,
                            int E, int NBLK, int B) {
    __shared__ int hist[MAXB];
    int t = threadIdx.x, b = blockIdx.x;
    for (int i = t; i < B; i += 256) hist[i] = 0;
    __syncthreads();
    int base = b * CH;
#pragma unroll
    for (int it = 0; it < CH / 256; it++) {
        int e = base + it * 256 + t;
        if (e < E) atomicAdd(&hist[eidx[E + e] >> 6], 1);
    }
    __syncthreads();
    for (int i = t; i < B; i += 256) histG[(size_t)i * NBLK + b] = hist[i];
}

__global__ void scan_l1(const int* __restrict__ data, int* __restrict__ bsum, int M) {
    __shared__ int sd[256];
    int t = threadIdx.x, b = blockIdx.x;
    int base = b * 1024 + t * 4;
    int ts = 0;
#pragma unroll
    for (int k = 0; k < 4; k++) { int i = base + k; if (i < M) ts += data[i]; }
    sd[t] = ts; __syncthreads();
    for (int s = 128; s > 0; s >>= 1) { if (t < s) sd[t] += sd[t + s]; __syncthreads(); }
    if (t == 0) bsum[b] = sd[0];
}

__global__ void scan_l2(int* __restrict__ bsum, int NB2) {
    __shared__ int sd[512];
    int t = threadIdx.x;
    int v = (t < NB2) ? bsum[t] : 0;
    sd[t] = v; __syncthreads();
    for (int o = 1; o < 512; o <<= 1) {
        int u = 0; if (t >= o) u = sd[t - o];
        __syncthreads(); sd[t] += u; __syncthreads();
    }
    if (t < NB2) bsum[t] = sd[t] - v;
}

__global__ void scan_l3(int* __restrict__ data, const int* __restrict__ bsum, int M) {
    __shared__ int sd[256];
    int t = threadIdx.x, b = blockIdx.x;
    int base = b * 1024 + t * 4;
    int c[4]; int ts = 0;
#pragma unroll
    for (int k = 0; k < 4; k++) { int i = base + k; c[k] = (i < M) ? data[i] : 0; ts += c[k]; }
    sd[t] = ts; __syncthreads();
    for (int o = 1; o < 256; o <<= 1) {
        int u = 0; if (t >= o) u = sd[t - o];
        __syncthreads(); sd[t] += u; __syncthreads();
    }
    int off = bsum[b] + sd[t] - ts;
#pragma unroll
    for (int k = 0; k < 4; k++) {
        int i = base + k;
        if (i < M) { data[i] = off; off += c[k]; }
    }
}

__global__ void phaseC_scatter(const int* __restrict__ eidx, const int* __restrict__ histG,
                               int* __restrict__ ebuf, int E, int NBLK, int B) {
    __shared__ int lofs[MAXB];
    int t = threadIdx.x, b = blockIdx.x;
    for (int i = t; i < B; i += 256) lofs[i] = histG[(size_t)i * NBLK + b];
    __syncthreads();
    int base = b * CH;
#pragma unroll
    for (int it = 0; it < CH / 256; it++) {
        int e = base + it * 256 + t;
        if (e < E) {
            int s = eidx[e], d = eidx[E + e];
            int pos = atomicAdd(&lofs[d >> 6], 1);
            ebuf[pos] = s | ((d & 63) << 17);
        }
    }
}

// Stage bucket in LDS, per-dl count + 64-lane scan -> off + dinv (into A and U),
// scatter src dl-sorted back in place.
__global__ void bucket_csr(int* __restrict__ ebuf, const int* __restrict__ histG,
                           int* __restrict__ off, char* __restrict__ A, char* __restrict__ U,
                           int E, int NBLK, int B, int n) {
    __shared__ int seg[SEGCAP];
    __shared__ int cnt[NPB];
    __shared__ int fillp[NPB];
    int t = threadIdx.x, k = blockIdx.x;
    if (t < NPB) cnt[t] = 0;
    int start = histG[(size_t)k * NBLK];
    int end = (k + 1 < B) ? histG[(size_t)(k + 1) * NBLK] : E;
    int len = end - start;
    if (len > SEGCAP) len = SEGCAP;
    __syncthreads();
    for (int i = t; i < len; i += 256) {
        int w = ebuf[start + i];
        seg[i] = w;
        atomicAdd(&cnt[w >> 17], 1);
    }
    __syncthreads();
    if (t < NPB) {
        int v = cnt[t];
        int x = v;
#pragma unroll
        for (int o2 = 1; o2 < 64; o2 <<= 1) {
            int y = __shfl_up(x, o2);
            if (t >= o2) x += y;
        }
        int excl = x - v;
        fillp[t] = excl;
        int d = k * NPB + t;
        if (d < n) {
            off[d] = start + excl;
            float dv = rsqrtf((float)(v + 1));
            *(float*)(A + (size_t)d * 32 + 16) = dv;
            *(float*)(U + (size_t)d * 64 + 48) = dv;
        }
    }
    if (k == 0 && t == 0) off[n] = E;
    __syncthreads();
    for (int i = t; i < len; i += 256) {
        int w = seg[i];
        int pos = atomicAdd(&fillp[w >> 17], 1);
        ebuf[start + pos] = w & 131071;
    }
}

// h0 = relu([emb[nidx], x] @ W1 + b1) -> A (fp16) and U ch0..7 (fp16)
__global__ void node_init(const float* __restrict__ x, const int* __restrict__ nidx,
                          const float* __restrict__ emb, const float* __restrict__ W1,
                          const float* __restrict__ b1, char* __restrict__ A,
                          char* __restrict__ U, int n) {
    int i = blockIdx.x * blockDim.x + threadIdx.x;
    if (i >= n) return;
    float in[24];
    int ni = nidx[i];
    const float4* ep = (const float4*)(emb + (size_t)ni * 8);
    float4 e0 = ep[0], e1 = ep[1];
    in[0] = e0.x; in[1] = e0.y; in[2] = e0.z; in[3] = e0.w;
    in[4] = e1.x; in[5] = e1.y; in[6] = e1.z; in[7] = e1.w;
    const float4* xp = (const float4*)(x + (size_t)i * 16);
#pragma unroll
    for (int t = 0; t < 4; t++) {
        float4 v = xp[t];
        in[8 + 4 * t + 0] = v.x; in[8 + 4 * t + 1] = v.y;
        in[8 + 4 * t + 2] = v.z; in[8 + 4 * t + 3] = v.w;
    }
    float acc[8];
#pragma unroll
    for (int j = 0; j < 8; j++) acc[j] = b1[j];
#pragma unroll
    for (int t = 0; t < 24; t++) {
        float xv = in[t];
#pragma unroll
        for (int j = 0; j < 8; j++) acc[j] = fmaf(xv, W1[t * 8 + j], acc[j]);
    }
    half8 h;
#pragma unroll
    for (int j = 0; j < 8; j++) h[j] = (_Float16)fmaxf(acc[j], 0.0f);
    *(half8*)(A + (size_t)i * 32) = h;
    *(half8*)(U + (size_t)i * 64) = h;
}

template <int Li>
__device__ __forceinline__ void attn_out(const float* xs, const float* qv,
                                         const float* __restrict__ wk, const float* __restrict__ bk,
                                         const float* __restrict__ wv, const float* __restrict__ bv,
                                         float* out) {
    float score[2][Li];
#pragma unroll
    for (int l = 0; l < Li; l++) {
#pragma unroll
        for (int h = 0; h < 2; h++) {
            float sc = 0.f;
#pragma unroll
            for (int dd = 0; dd < 4; dd++) {
                int c = h * 4 + dd;
                sc = fmaf(qv[c], fmaf(xs[l * 8 + c], wk[c], bk[c]), sc);
            }
            score[h][l] = 0.5f * sc;
        }
    }
    float attn[2][Li];
#pragma unroll
    for (int h = 0; h < 2; h++) {
        float m = score[h][0];
#pragma unroll
        for (int l = 1; l < Li; l++) m = fmaxf(m, score[h][l]);
        float ssum = 0.f;
#pragma unroll
        for (int l = 0; l < Li; l++) { attn[h][l] = __expf(score[h][l] - m); ssum += attn[h][l]; }
        float inv = 1.0f / ssum;
#pragma unroll
        for (int l = 0; l < Li; l++) attn[h][l] *= inv;
    }
#pragma unroll
    for (int c = 0; c < 8; c++) {
        int h = c >> 2;
        float o = 0.f;
#pragma unroll
        for (int l = 0; l < Li; l++) o = fmaf(attn[h][l], fmaf(xs[l * 8 + c], wv[c], bv[c]), o);
        out[c] = o;
    }
}

// 8 lanes per dst; virtual slot 0 = self-loop; register acc + shfl_xor reduce.
// Li=1 reads A (3.2 MB), writes U ch8..15. Li=2 reads U ch0..15, writes ch16..23.
// Li=3 reads full U, fuses classifier + log_softmax.
template <int Li, bool LAST>
__global__ void agg_layer(const int* __restrict__ ssrc, const int* __restrict__ off,
                          const char* __restrict__ A, char* __restrict__ U,
                          const float* __restrict__ wq, const float* __restrict__ bq,
                          const float* __restrict__ wk, const float* __restrict__ bk,
                          const float* __restrict__ wv, const float* __restrict__ bv,
                          const float* __restrict__ W2, const float* __restrict__ b2,
                          float* __restrict__ out, int n) {
    int tid = blockIdx.x * blockDim.x + threadIdx.x;
    int d = tid >> 3, t = tid & 7;
    if (d >= n) return;
    int lo = off[d], cnt = off[d + 1] - lo;

    // q from previous layer's output of dst
    float qv[8];
    {
        half8 qh;
        if (Li == 1) qh = *(const half8*)(A + (size_t)d * 32);
        else         qh = *(const half8*)(U + (size_t)d * 64 + (Li - 1) * 16);
#pragma unroll
        for (int c = 0; c < 8; c++) qv[c] = fmaf((float)qh[c], wq[c], bq[c]);
    }

    float acc[8];
#pragma unroll
    for (int c = 0; c < 8; c++) acc[c] = 0.f;

    for (int j = t; j < cnt + 1; j += 8) {
        int s = (j == 0) ? d : ssrc[lo + j - 1];
        float xs[8 * Li];
        float ns;
        if (Li == 1) {
            half8 h = *(const half8*)(A + (size_t)s * 32);
#pragma unroll
            for (int c = 0; c < 8; c++) xs[c] = (float)h[c];
            ns = *(const float*)(A + (size_t)s * 32 + 16);
        } else {
            const char* ub = U + (size_t)s * 64;
#pragma unroll
            for (int l = 0; l < Li; l++) {
                half8 h = *(const half8*)(ub + l * 16);
#pragma unroll
                for (int c = 0; c < 8; c++) xs[l * 8 + c] = (float)h[c];
            }
            ns = *(const float*)(ub + 48);
        }
        float o[8];
        attn_out<Li>(xs, qv, wk, bk, wv, bv, o);
#pragma unroll
        for (int c = 0; c < 8; c++) acc[c] = fmaf(o[c], ns, acc[c]);
    }
#pragma unroll
    for (int m = 1; m < 8; m <<= 1) {
#pragma unroll
        for (int c = 0; c < 8; c++) acc[c] += __shfl_xor(acc[c], m);
    }
    float nd = (Li == 1) ? *(const float*)(A + (size_t)d * 32 + 16)
                         : *(const float*)(U + (size_t)d * 64 + 48);
    if (!LAST) {
        float h = fmaxf(acc[t] * nd, 0.f);
        *(_Float16*)(U + (size_t)d * 64 + Li * 16 + 2 * t) = (_Float16)h;
    } else if (t == 0) {
        float z0 = b2[0], z1 = b2[1];
#pragma unroll
        for (int c = 0; c < 8; c++) {
            float h = fmaxf(acc[c] * nd, 0.f);
            z0 = fmaf(h, W2[c * 2 + 0], z0);
            z1 = fmaf(h, W2[c * 2 + 1], z1);
        }
        float m = fmaxf(z0, z1);
        float lse = m + logf(__expf(z0 - m) + __expf(z1 - m));
        ((float2*)out)[d] = make_float2(z0 - lse, z1 - lse);
    }
}

extern "C" void kernel_launch(void* const* d_in, const int* in_sizes, int n_in,
                              void* d_out, int out_size, void* d_ws, size_t ws_size,
                              hipStream_t stream) {
    const float* x    = (const float*)d_in[0];
    const int*   nidx = (const int*)d_in[1];
    const int*   eidx = (const int*)d_in[3];
    const float* emb  = (const float*)d_in[5];
    const float* W1   = (const float*)d_in[6];
    const float* b1   = (const float*)d_in[7];
    const float* Wq   = (const float*)d_in[8];
    const float* bq   = (const float*)d_in[9];
    const float* Wk   = (const float*)d_in[10];
    const float* bk   = (const float*)d_in[11];
    const float* Wv   = (const float*)d_in[12];
    const float* bv   = (const float*)d_in[13];
    const float* W2   = (const float*)d_in[14];
    const float* b2   = (const float*)d_in[15];
    float* out = (float*)d_out;

    const int n = in_sizes[0] / 16;            // 100000
    const int E = in_sizes[3] / 2;             // 3200000
    const int B = (n + NPB - 1) / NPB;         // 1563
    const int NBLK = (E + CH - 1) / CH;        // 196
    const int M = B * NBLK;
    const int NB2 = (M + 1023) / 1024;

    char* wsp = (char*)d_ws;
    char*  A     = wsp;          wsp += (size_t)n * 32;
    char*  U     = wsp;          wsp += (size_t)n * 64;
    int*   ebuf  = (int*)wsp;    wsp += (size_t)E * 4;
    int*   off   = (int*)wsp;    wsp += (size_t)(n + 1) * 4;
    int*   histG = (int*)wsp;    wsp += (size_t)M * 4;
    int*   bsum  = (int*)wsp;

    dim3 blk(256);
    dim3 gn((n + 255) / 256);
    dim3 ga(((size_t)n * 8 + 255) / 256);

    phaseA_hist<<<NBLK, blk, 0, stream>>>(eidx, histG, E, NBLK, B);
    scan_l1<<<NB2, blk, 0, stream>>>(histG, bsum, M);
    scan_l2<<<1, 512, 0, stream>>>(bsum, NB2);
    scan_l3<<<NB2, blk, 0, stream>>>(histG, bsum, M);
    phaseC_scatter<<<NBLK, blk, 0, stream>>>(eidx, histG, ebuf, E, NBLK, B);
    bucket_csr<<<B, blk, 0, stream>>>(ebuf, histG, off, A, U, E, NBLK, B, n);
    node_init<<<gn, blk, 0, stream>>>(x, nidx, emb, W1, b1, A, U, n);

    agg_layer<1, false><<<ga, blk, 0, stream>>>(ebuf, off, A, U,
        Wq, bq, Wk, bk, Wv, bv, W2, b2, out, n);
    agg_layer<2, false><<<ga, blk, 0, stream>>>(ebuf, off, A, U,
        Wq + 8, bq + 8, Wk + 8, bk + 8, Wv + 8, bv + 8, W2, b2, out, n);
    agg_layer<3, true><<<ga, blk, 0, stream>>>(ebuf, off, A, U,
        Wq + 16, bq + 16, Wk + 16, bk + 16, Wv + 16, bv + 16, W2, b2, out, n);
}